// Round 1
// baseline (347.753 us; speedup 1.0000x reference)
//
#include <hip/hip_runtime.h>
#include <math.h>

#define EPS 1e-8f
#define BB 32
#define SS 64
#define HH 200
#define LL 20

// ---------------------------------------------------------------- sq: w3^2 / w4^2
__global__ void sq_kernel(const float* __restrict__ w3, const float* __restrict__ w4,
                          float* __restrict__ w2sq) {
    int idx = blockIdx.x * 256 + threadIdx.x;
    if (idx >= 2 * LL * HH) return;
    int dir = idx / (LL * HH);
    int r = idx % (LL * HH);
    float v = (dir == 0 ? w3 : w4)[r];
    w2sq[idx] = v * v;
}

// ---------------------------------------------------------------- attention matrices
// grid: (dir*BB + b)*SS + p ; 64 threads = q
__global__ void att_kernel(const float* __restrict__ conp, const float* __restrict__ conh,
                           float* __restrict__ att) {
    int blk = blockIdx.x;
    int p = blk % SS; int t = blk / SS; int b = t % BB; int dir = t / BB;
    int q = threadIdx.x;
    const float* pv = conp + (b * SS + p) * (2 * HH) + dir * HH;
    const float* hv = conh + (b * SS + q) * (2 * HH) + dir * HH;
    float dot = 0.f, pp = 0.f, qq = 0.f;
    for (int h = 0; h < HH; ++h) {
        float a = pv[h], c = hv[h];
        dot = fmaf(a, c, dot);
        pp  = fmaf(a, a, pp);
        qq  = fmaf(c, c, qq);
    }
    att[blk * SS + q] = dot / fmaxf(sqrtf(pp) * sqrtf(qq), EPS);
}

// ---------------------------------------------------------------- weighted norms (pairwise, w3/w4)
// grid: ((side*2+dir)*BB + b)*SS + s ; 64 threads, lane l<20 active
__global__ void wnorm_kernel(const float* __restrict__ conp, const float* __restrict__ conh,
                             const float* __restrict__ w2sq, float* __restrict__ wn) {
    int blk = blockIdx.x;
    int s = blk % SS; int t = blk / SS; int b = t % BB; t /= BB;
    int dir = t & 1; int side = t >> 1;
    int l = threadIdx.x;
    if (l >= LL) return;
    const float* v  = (side == 0 ? conp : conh) + (b * SS + s) * (2 * HH) + dir * HH;
    const float* w2 = w2sq + dir * (LL * HH) + l * HH;
    float acc = 0.f;
    for (int h = 0; h < HH; ++h) { float vv = v[h]; acc = fmaf(vv * vv, w2[h], acc); }
    wn[blk * LL + l] = sqrtf(acc);
}

// ---------------------------------------------------------------- mp_match: full / att_mean / att_max
// grid: ((side*2+dir)*BB + b)*SS + s ; 256 threads
__global__ void match_kernel(const float* __restrict__ conp, const float* __restrict__ conh,
                             const float* __restrict__ att,
                             const float* __restrict__ w1, const float* __restrict__ w2,
                             const float* __restrict__ w5, const float* __restrict__ w6,
                             const float* __restrict__ w7, const float* __restrict__ w8,
                             float* __restrict__ out) {
    int blk = blockIdx.x;
    int s = blk % SS; int t = blk / SS; int b = t % BB; t /= BB;
    int dir = t & 1; int side = t >> 1;
    int tid = threadIdx.x;
    __shared__ float meanv[HH], maxv[HH];
    __shared__ float pd[240], pa[240], pb[240];
    const float* v1  = (side == 0 ? conp : conh) + (b * SS + s) * (2 * HH) + dir * HH;
    const float* opp = (side == 0 ? conh : conp);

    // phase 1: att-weighted mean & max vectors over the opposite sequence
    if (tid < HH) {
        float msum = 0.f, mmax = -INFINITY, asum = 0.f;
        for (int k = 0; k < SS; ++k) {
            float a = (side == 0) ? att[((dir * BB + b) * SS + s) * SS + k]
                                  : att[((dir * BB + b) * SS + k) * SS + s];
            float v = opp[(b * SS + k) * (2 * HH) + dir * HH + tid];
            msum = fmaf(a, v, msum);
            mmax = fmaxf(mmax, a * v);
            asum += a;
        }
        meanv[tid] = msum / fmaxf(asum, EPS);
        maxv[tid]  = mmax;
    }
    __syncthreads();

    // phase 2: 3 mp_matches (m=0 full, m=1 att_mean, m=2 att_max), 4-way split over H
    if (tid < 240) {
        int m = tid / 80, r = tid % 80, l = r >> 2, c = r & 3;
        const float* w = (m == 0 ? (dir == 0 ? w1 : w2)
                       : (m == 1 ? (dir == 0 ? w5 : w6)
                                 : (dir == 0 ? w7 : w8))) + l * HH;
        int fidx = (dir == 0) ? (SS - 1) : 0;
        const float* fv = opp + (b * SS + fidx) * (2 * HH) + dir * HH;
        float dacc = 0.f, aacc = 0.f, bacc = 0.f;
        for (int h = c; h < HH; h += 4) {
            float wv = w[h]; float w2v = wv * wv;
            float x = v1[h];
            float y = (m == 0) ? fv[h] : (m == 1) ? meanv[h] : maxv[h];
            dacc = fmaf(x * y, w2v, dacc);
            aacc = fmaf(x * x, w2v, aacc);
            bacc = fmaf(y * y, w2v, bacc);
        }
        pd[tid] = dacc; pa[tid] = aacc; pb[tid] = bacc;
    }
    __syncthreads();

    if (tid < 60) {
        int m = tid / 20, l = tid % 20;
        int base = m * 80 + l * 4;
        float dacc = pd[base] + pd[base + 1] + pd[base + 2] + pd[base + 3];
        float aacc = pa[base] + pa[base + 1] + pa[base + 2] + pa[base + 3];
        float bacc = pb[base] + pb[base + 1] + pb[base + 2] + pb[base + 3];
        float r = dacc / fmaxf(sqrtf(aacc * bacc), EPS);
        int chunk = (m == 0) ? 0 : (m == 1) ? 40 : 60;
        out[side * (BB * SS * 160) + (b * SS + s) * 160 + dir * 80 + chunk + l] = r;
    }
}

// ---------------------------------------------------------------- pairwise cosine + max over lanes
// grid: (dir*BB + b)*SS + i ; 64 threads = j (opposite sequence index)
// side=0: rows=p (max over q -> mv_p chunk); side=1: rows=q (max over p -> mv_h chunk)
__global__ void pairwise_kernel(const float* __restrict__ conp, const float* __restrict__ conh,
                                const float* __restrict__ w2sq, const float* __restrict__ wn,
                                float* __restrict__ out, int side) {
    int blk = blockIdx.x;
    int i = blk % SS; int t = blk / SS; int b = t % BB; int dir = t / BB;
    int j = threadIdx.x;
    const float* A  = (side == 0 ? conp : conh) + (b * SS + i) * (2 * HH) + dir * HH; // uniform
    const float* Bv = (side == 0 ? conh : conp) + (b * SS + j) * (2 * HH) + dir * HH; // per lane
    const float* w2 = w2sq + dir * (LL * HH);

    float acc[LL];
#pragma unroll
    for (int l = 0; l < LL; ++l) acc[l] = 0.f;

    const float4* A4 = (const float4*)A;
    const float4* B4 = (const float4*)Bv;
    for (int h4 = 0; h4 < HH / 4; ++h4) {
        float4 av = A4[h4];
        float4 bv = B4[h4];
        float e0 = av.x * bv.x, e1 = av.y * bv.y, e2 = av.z * bv.z, e3 = av.w * bv.w;
        int h = h4 * 4;
#pragma unroll
        for (int l = 0; l < LL; ++l) {
            const float* wr = w2 + l * HH + h;   // uniform address -> scalar loads
            acc[l] = fmaf(e0, wr[0], acc[l]);
            acc[l] = fmaf(e1, wr[1], acc[l]);
            acc[l] = fmaf(e2, wr[2], acc[l]);
            acc[l] = fmaf(e3, wr[3], acc[l]);
        }
    }

    const float* na = wn + (((side * 2 + dir) * BB + b) * SS + i) * LL;        // uniform
    const float* nb = wn + ((((1 - side) * 2 + dir) * BB + b) * SS + j) * LL;  // per lane

#pragma unroll
    for (int l = 0; l < LL; ++l) {
        float c = acc[l] / fmaxf(na[l] * nb[l], EPS);
#pragma unroll
        for (int off = 32; off >= 1; off >>= 1)
            c = fmaxf(c, __shfl_xor(c, off, 64));
        acc[l] = c;  // all lanes now hold max over j
    }

    if (j == 0) {
        float* o = out + side * (BB * SS * 160) + (b * SS + i) * 160 + dir * 80 + 20;
#pragma unroll
        for (int l = 0; l < LL; ++l) o[l] = acc[l];
    }
}

extern "C" void kernel_launch(void* const* d_in, const int* in_sizes, int n_in,
                              void* d_out, int out_size, void* d_ws, size_t ws_size,
                              hipStream_t stream) {
    const float* conp = (const float*)d_in[0];
    const float* conh = (const float*)d_in[1];
    const float* w1 = (const float*)d_in[2];
    const float* w2 = (const float*)d_in[3];
    const float* w3 = (const float*)d_in[4];
    const float* w4 = (const float*)d_in[5];
    const float* w5 = (const float*)d_in[6];
    const float* w6 = (const float*)d_in[7];
    const float* w7 = (const float*)d_in[8];
    const float* w8 = (const float*)d_in[9];
    float* out = (float*)d_out;
    float* ws  = (float*)d_ws;

    float* att   = ws;                        // 2*BB*SS*SS  = 262144 floats
    float* wn    = att + 2 * BB * SS * SS;    // 4*BB*SS*LL  = 163840 floats
    float* w2sq  = wn + 4 * BB * SS * LL;     // 2*LL*HH     = 8000 floats

    sq_kernel<<<(2 * LL * HH + 255) / 256, 256, 0, stream>>>(w3, w4, w2sq);
    att_kernel<<<2 * BB * SS, 64, 0, stream>>>(conp, conh, att);
    wnorm_kernel<<<4 * BB * SS, 64, 0, stream>>>(conp, conh, w2sq, wn);
    match_kernel<<<4 * BB * SS, 256, 0, stream>>>(conp, conh, att, w1, w2, w5, w6, w7, w8, out);
    pairwise_kernel<<<2 * BB * SS, 64, 0, stream>>>(conp, conh, w2sq, wn, out, 0);
    pairwise_kernel<<<2 * BB * SS, 64, 0, stream>>>(conp, conh, w2sq, wn, out, 1);
}

// Round 3
// 302.965 us; speedup vs baseline: 1.1478x; 1.1478x over previous
//
#include <hip/hip_runtime.h>
#include <math.h>

#define EPS 1e-8f
#define BB 32
#define SS 64
#define HH 200
#define LL 20

// ws layout (floats):
// att 262144 | rowsum 4096 | attcol 4096 | n2arr 8192 | wn 163840
// w2sq 8000 [dir][l][h] | w2pt 8000 [dir][h2][l][2] | w2t 24000 [dir*3+m][h2][l][2]
// meanv 1638400 | maxv 1638400   -> total ~15.0 MB

// ---------------------------------------------------------------- squared weights (3 layouts)
__global__ void sq_kernel(const float* __restrict__ w1, const float* __restrict__ w2,
                          const float* __restrict__ w3, const float* __restrict__ w4,
                          const float* __restrict__ w5, const float* __restrict__ w6,
                          const float* __restrict__ w7, const float* __restrict__ w8,
                          float* __restrict__ w2sq, float* __restrict__ w2pt,
                          float* __restrict__ w2t) {
    int idx = blockIdx.x * 256 + threadIdx.x;
    if (idx >= 2 * LL * HH) return;
    int dir = idx / (LL * HH);
    int r = idx % (LL * HH);
    int l = r / HH, h = r % HH;
    int h2 = h >> 1, comp = h & 1;
    float v = (dir == 0 ? w3 : w4)[l * HH + h];
    float sqv = v * v;
    w2sq[idx] = sqv;                                   // [dir][l][h]
    w2pt[(dir * 100 + h2) * 40 + l * 2 + comp] = sqv;  // [dir][h2][l][2]
    const float* wa = dir ? w2 : w1;
    const float* wb = dir ? w6 : w5;
    const float* wc = dir ? w8 : w7;
    float ua = wa[l * HH + h], ub = wb[l * HH + h], uc = wc[l * HH + h];
    w2t[((dir * 3 + 0) * 100 + h2) * 40 + l * 2 + comp] = ua * ua;
    w2t[((dir * 3 + 1) * 100 + h2) * 40 + l * 2 + comp] = ub * ub;
    w2t[((dir * 3 + 2) * 100 + h2) * 40 + l * 2 + comp] = uc * uc;
}

// ---------------------------------------------------------------- plain norms: [side][dir][b][s]
__global__ void pnorm_kernel(const float* __restrict__ conp, const float* __restrict__ conh,
                             float* __restrict__ n2arr) {
    int t = threadIdx.x;
    int wave = t >> 6, lane = t & 63;
    int e = blockIdx.x * 4 + wave;
    int s = e & 63, b = (e >> 6) & 31, sd = e >> 11;
    int dir = sd & 1, side = sd >> 1;
    const float* v = (side ? conh : conp) + (b * SS + s) * (2 * HH) + dir * HH;
    float val = 0.f;
    if (lane < 50) {
        float4 f = ((const float4*)v)[lane];
        val = f.x * f.x + f.y * f.y + f.z * f.z + f.w * f.w;
    }
#pragma unroll
    for (int off = 32; off >= 1; off >>= 1) val += __shfl_xor(val, off, 64);
    if (lane == 0) n2arr[e] = sqrtf(val);
}

// ---------------------------------------------------------------- attention matrix + row sums
// blk = (dir*BB+b)*SS + p ; lanes = q
__global__ void att_kernel(const float* __restrict__ conp, const float* __restrict__ conh,
                           const float* __restrict__ n2arr,
                           float* __restrict__ att, float* __restrict__ rowsum) {
    int blk = blockIdx.x;
    int p = blk & 63, b = (blk >> 6) & 31, dir = blk >> 11;
    int q = threadIdx.x;
    __shared__ float4 pvL[50];
    const float* pv = conp + (b * SS + p) * (2 * HH) + dir * HH;
    if (q < 50) pvL[q] = ((const float4*)pv)[q];
    __syncthreads();
    const float4* hv = (const float4*)(conh + (b * SS + q) * (2 * HH) + dir * HH);
    float dot = 0.f;
    for (int j = 0; j < 50; ++j) {
        float4 a = pvL[j]; float4 c = hv[j];
        dot = fmaf(a.x, c.x, dot); dot = fmaf(a.y, c.y, dot);
        dot = fmaf(a.z, c.z, dot); dot = fmaf(a.w, c.w, dot);
    }
    float n1 = n2arr[((0 * 2 + dir) * BB + b) * SS + p];
    float n2 = n2arr[((1 * 2 + dir) * BB + b) * SS + q];
    float a = dot / fmaxf(n1 * n2, EPS);
    att[blk * SS + q] = a;
    float rs = a;
#pragma unroll
    for (int off = 32; off >= 1; off >>= 1) rs += __shfl_xor(rs, off, 64);
    if (q == 0) rowsum[blk] = rs;
}

// ---------------------------------------------------------------- column sums of att
__global__ void colsum_kernel(const float* __restrict__ att, float* __restrict__ attcol) {
    int blk = blockIdx.x;  // dir*BB + b
    int q = threadIdx.x;
    const float* base = att + blk * SS * SS;
    float acc = 0.f;
    for (int p = 0; p < SS; ++p) acc += base[p * SS + q];
    attcol[blk * SS + q] = acc;
}

// ---------------------------------------------------------------- att-mean & att-max vectors
// blk = ((side*2+dir)*BB + b)*8 + ht ; 256 threads: s = t>>2, c3 = t&3
__global__ void attvec_kernel(const float* __restrict__ conp, const float* __restrict__ conh,
                              const float* __restrict__ att,
                              const float* __restrict__ rowsum, const float* __restrict__ attcol,
                              float* __restrict__ meanv, float* __restrict__ maxv) {
    int blk = blockIdx.x;
    int ht = blk & 7, b = (blk >> 3) & 31, sd = blk >> 8;
    int dir = sd & 1, side = sd >> 1;
    int t = threadIdx.x;
    __shared__ float attL[SS * 65];
    __shared__ float oppL[SS * 26];
    const float* abase = att + (dir * BB + b) * SS * SS;
    for (int e = t; e < SS * SS; e += 256) {
        int r = e >> 6, c = e & 63;
        float v = abase[e];
        if (side == 0) attL[r * 65 + c] = v;
        else           attL[c * 65 + r] = v;
    }
    const float* opp = (side == 0 ? conh : conp);
    for (int e = t; e < SS * 25; e += 256) {
        int k = e / 25, j = e - k * 25;
        oppL[k * 26 + j] = opp[(b * SS + k) * (2 * HH) + dir * HH + ht * 25 + j];
    }
    __syncthreads();
    int s = t >> 2, c3 = t & 3;
    int j0 = c3 * 7;
    float ms[7], mx[7];
#pragma unroll
    for (int i = 0; i < 7; ++i) { ms[i] = 0.f; mx[i] = -INFINITY; }
    for (int k = 0; k < SS; ++k) {
        float a = attL[s * 65 + k];
        int base = k * 26 + j0;
#pragma unroll
        for (int i = 0; i < 7; ++i) {
            if (j0 + i < 25) {
                float tt = a * oppL[base + i];
                ms[i] += tt;
                mx[i] = fmaxf(mx[i], tt);
            }
        }
    }
    float dn = (side == 0) ? rowsum[(dir * BB + b) * SS + s] : attcol[(dir * BB + b) * SS + s];
    float dd = fmaxf(dn, EPS);
    int obase = (((side * 2 + dir) * BB + b) * SS + s) * HH + ht * 25 + j0;
#pragma unroll
    for (int i = 0; i < 7; ++i) {
        if (j0 + i < 25) {
            meanv[obase + i] = ms[i] / dd;
            maxv[obase + i]  = mx[i];
        }
    }
}

// ---------------------------------------------------------------- mp_match (full/mean/max) + wn
// blk = ((side*2+dir)*BB + b)*SS + s ; 64 threads, lane = (m,l)
__global__ void match_kernel(const float* __restrict__ conp, const float* __restrict__ conh,
                             const float* __restrict__ meanv, const float* __restrict__ maxv,
                             const float* __restrict__ w2t, const float* __restrict__ w2pt,
                             float* __restrict__ out, float* __restrict__ wn) {
    int blk = blockIdx.x;
    int s = blk & 63, b = (blk >> 6) & 31, sd = blk >> 11;
    int dir = sd & 1, side = sd >> 1;
    int t = threadIdx.x;
    __shared__ __align__(16) float x2L[HH];
    __shared__ __align__(16) float xyL[3][HH];
    __shared__ __align__(16) float y2L[3][HH];
    const float* v1 = (side == 0 ? conp : conh) + (b * SS + s) * (2 * HH) + dir * HH;
    const float* opp = (side == 0 ? conh : conp);
    int fidx = (dir == 0) ? (SS - 1) : 0;
    const float* fv = opp + (b * SS + fidx) * (2 * HH) + dir * HH;
    const float* mv = meanv + (((side * 2 + dir) * BB + b) * SS + s) * HH;
    const float* xv = maxv  + (((side * 2 + dir) * BB + b) * SS + s) * HH;
    for (int h = t; h < HH; h += 64) {
        float x = v1[h];
        x2L[h] = x * x;
        float y0 = fv[h], y1 = mv[h], y2v = xv[h];
        xyL[0][h] = x * y0;  y2L[0][h] = y0 * y0;
        xyL[1][h] = x * y1;  y2L[1][h] = y1 * y1;
        xyL[2][h] = x * y2v; y2L[2][h] = y2v * y2v;
    }
    __syncthreads();
    if (t < 60) {
        int m = t / 20, l = t - m * 20;
        const float* wt = w2t + (dir * 3 + m) * 4000 + l * 2;
        float d0 = 0, d1 = 0, a0 = 0, a1 = 0, b0 = 0, b1 = 0;
        for (int h2 = 0; h2 < 100; ++h2) {
            float2 w  = *(const float2*)(wt + h2 * 40);
            float2 xy = *(const float2*)&xyL[m][h2 * 2];
            float2 x2 = *(const float2*)&x2L[h2 * 2];
            float2 yy = *(const float2*)&y2L[m][h2 * 2];
            d0 = fmaf(xy.x, w.x, d0); d1 = fmaf(xy.y, w.y, d1);
            a0 = fmaf(x2.x, w.x, a0); a1 = fmaf(x2.y, w.y, a1);
            b0 = fmaf(yy.x, w.x, b0); b1 = fmaf(yy.y, w.y, b1);
        }
        float d = d0 + d1, a = a0 + a1, bb2 = b0 + b1;
        float cosv = d / fmaxf(sqrtf(a * bb2), EPS);
        int chunk = (m == 0) ? 0 : (m == 1) ? 40 : 60;
        out[side * (BB * SS * 160) + (b * SS + s) * 160 + dir * 80 + chunk + l] = cosv;
    }
    if (t < 20) {
        const float* pw = w2pt + dir * 4000 + t * 2;
        float n0 = 0, n1v = 0;
        for (int h2 = 0; h2 < 100; ++h2) {
            float2 w  = *(const float2*)(pw + h2 * 40);
            float2 x2 = *(const float2*)&x2L[h2 * 2];
            n0  = fmaf(x2.x, w.x, n0);
            n1v = fmaf(x2.y, w.y, n1v);
        }
        wn[blk * LL + t] = sqrtf(n0 + n1v);
    }
}

// ---------------------------------------------------------------- pairwise cosine + max over lanes
__global__ void pairwise_kernel(const float* __restrict__ conp, const float* __restrict__ conh,
                                const float* __restrict__ w2sq, const float* __restrict__ wn,
                                float* __restrict__ out, int side) {
    int blk = blockIdx.x;
    int i = blk % SS; int t = blk / SS; int b = t % BB; int dir = t / BB;
    int j = threadIdx.x;
    const float* A  = (side == 0 ? conp : conh) + (b * SS + i) * (2 * HH) + dir * HH; // uniform
    const float* Bv = (side == 0 ? conh : conp) + (b * SS + j) * (2 * HH) + dir * HH; // per lane
    const float* w2 = w2sq + dir * (LL * HH);

    float acc[LL];
#pragma unroll
    for (int l = 0; l < LL; ++l) acc[l] = 0.f;

    const float4* A4 = (const float4*)A;
    const float4* B4 = (const float4*)Bv;
    for (int h4 = 0; h4 < HH / 4; ++h4) {
        float4 av = A4[h4];
        float4 bv = B4[h4];
        float e0 = av.x * bv.x, e1 = av.y * bv.y, e2 = av.z * bv.z, e3 = av.w * bv.w;
        int h = h4 * 4;
#pragma unroll
        for (int l = 0; l < LL; ++l) {
            const float* wr = w2 + l * HH + h;   // uniform address -> scalar loads
            acc[l] = fmaf(e0, wr[0], acc[l]);
            acc[l] = fmaf(e1, wr[1], acc[l]);
            acc[l] = fmaf(e2, wr[2], acc[l]);
            acc[l] = fmaf(e3, wr[3], acc[l]);
        }
    }

    const float* na = wn + (((side * 2 + dir) * BB + b) * SS + i) * LL;        // uniform
    const float* nb = wn + ((((1 - side) * 2 + dir) * BB + b) * SS + j) * LL;  // per lane

#pragma unroll
    for (int l = 0; l < LL; ++l) {
        float c = acc[l] / fmaxf(na[l] * nb[l], EPS);
#pragma unroll
        for (int off = 32; off >= 1; off >>= 1)
            c = fmaxf(c, __shfl_xor(c, off, 64));
        acc[l] = c;
    }

    if (j == 0) {
        float* o = out + side * (BB * SS * 160) + (b * SS + i) * 160 + dir * 80 + 20;
#pragma unroll
        for (int l = 0; l < LL; ++l) o[l] = acc[l];
    }
}

extern "C" void kernel_launch(void* const* d_in, const int* in_sizes, int n_in,
                              void* d_out, int out_size, void* d_ws, size_t ws_size,
                              hipStream_t stream) {
    const float* conp = (const float*)d_in[0];
    const float* conh = (const float*)d_in[1];
    const float* w1 = (const float*)d_in[2];
    const float* w2 = (const float*)d_in[3];
    const float* w3 = (const float*)d_in[4];
    const float* w4 = (const float*)d_in[5];
    const float* w5 = (const float*)d_in[6];
    const float* w6 = (const float*)d_in[7];
    const float* w7 = (const float*)d_in[8];
    const float* w8 = (const float*)d_in[9];
    float* out = (float*)d_out;
    float* ws  = (float*)d_ws;

    float* att    = ws;                        // 262144
    float* rowsum = att + 2 * BB * SS * SS;    // 4096
    float* attcol = rowsum + 2 * BB * SS;      // 4096
    float* n2arr  = attcol + 2 * BB * SS;      // 8192
    float* wn     = n2arr + 4 * BB * SS;       // 163840
    float* w2sq   = wn + 4 * BB * SS * LL;     // 8000
    float* w2pt   = w2sq + 2 * LL * HH;        // 8000
    float* w2t    = w2pt + 2 * LL * HH;        // 24000
    float* meanv  = w2t + 6 * LL * HH;         // 1638400
    float* maxv   = meanv + 4 * BB * SS * HH;  // 1638400

    sq_kernel<<<(2 * LL * HH + 255) / 256, 256, 0, stream>>>(w1, w2, w3, w4, w5, w6, w7, w8,
                                                             w2sq, w2pt, w2t);
    pnorm_kernel<<<4 * BB * SS / 4, 256, 0, stream>>>(conp, conh, n2arr);
    att_kernel<<<2 * BB * SS, 64, 0, stream>>>(conp, conh, n2arr, att, rowsum);
    colsum_kernel<<<2 * BB, 64, 0, stream>>>(att, attcol);
    attvec_kernel<<<4 * BB * 8, 256, 0, stream>>>(conp, conh, att, rowsum, attcol, meanv, maxv);
    match_kernel<<<4 * BB * SS, 64, 0, stream>>>(conp, conh, meanv, maxv, w2t, w2pt, out, wn);
    pairwise_kernel<<<2 * BB * SS, 64, 0, stream>>>(conp, conh, w2sq, wn, out, 0);
    pairwise_kernel<<<2 * BB * SS, 64, 0, stream>>>(conp, conh, w2sq, wn, out, 1);
}

// Round 4
// 245.163 us; speedup vs baseline: 1.4185x; 1.2358x over previous
//
#include <hip/hip_runtime.h>
#include <math.h>

#define EPS 1e-8f
#define BB 32
#define SS 64
#define HH 200
#define LL 20

// ws layout (floats):
// att 262144 | rowsum 4096 | attcol 4096 | n2arr 8192 | wn 163840
// w2c 8000 [dir][h4][l][4] | w2pt 8000 [dir][h2][l][2] | w2t 24000 [dir*3+m][h2][l][2]
// meanv 1638400 | maxv 1638400 | pcm 655360 [itile][dirb][j][l]  -> ~17.7 MB

// ---------------------------------------------------------------- squared weights (3 layouts)
__global__ void sq_kernel(const float* __restrict__ w1, const float* __restrict__ w2,
                          const float* __restrict__ w3, const float* __restrict__ w4,
                          const float* __restrict__ w5, const float* __restrict__ w6,
                          const float* __restrict__ w7, const float* __restrict__ w8,
                          float* __restrict__ w2c, float* __restrict__ w2pt,
                          float* __restrict__ w2t) {
    int idx = blockIdx.x * 256 + threadIdx.x;
    if (idx >= 2 * LL * HH) return;
    int dir = idx / (LL * HH);
    int r = idx % (LL * HH);
    int l = r / HH, h = r % HH;
    int h2 = h >> 1, comp = h & 1;
    float v = (dir == 0 ? w3 : w4)[l * HH + h];
    float sqv = v * v;
    w2c[dir * 4000 + (h >> 2) * 80 + l * 4 + (h & 3)] = sqv;  // [dir][h4][l][4]
    w2pt[(dir * 100 + h2) * 40 + l * 2 + comp] = sqv;          // [dir][h2][l][2]
    const float* wa = dir ? w2 : w1;
    const float* wb = dir ? w6 : w5;
    const float* wc = dir ? w8 : w7;
    float ua = wa[l * HH + h], ub = wb[l * HH + h], uc = wc[l * HH + h];
    w2t[((dir * 3 + 0) * 100 + h2) * 40 + l * 2 + comp] = ua * ua;
    w2t[((dir * 3 + 1) * 100 + h2) * 40 + l * 2 + comp] = ub * ub;
    w2t[((dir * 3 + 2) * 100 + h2) * 40 + l * 2 + comp] = uc * uc;
}

// ---------------------------------------------------------------- plain norms: [side][dir][b][s]
__global__ void pnorm_kernel(const float* __restrict__ conp, const float* __restrict__ conh,
                             float* __restrict__ n2arr) {
    int t = threadIdx.x;
    int wave = t >> 6, lane = t & 63;
    int e = blockIdx.x * 4 + wave;
    int s = e & 63, b = (e >> 6) & 31, sd = e >> 11;
    int dir = sd & 1, side = sd >> 1;
    const float* v = (side ? conh : conp) + (b * SS + s) * (2 * HH) + dir * HH;
    float val = 0.f;
    if (lane < 50) {
        float4 f = ((const float4*)v)[lane];
        val = f.x * f.x + f.y * f.y + f.z * f.z + f.w * f.w;
    }
#pragma unroll
    for (int off = 32; off >= 1; off >>= 1) val += __shfl_xor(val, off, 64);
    if (lane == 0) n2arr[e] = sqrtf(val);
}

// ---------------------------------------------------------------- attention matrix + row sums
// blk = (dir*BB+b)*SS + p ; lanes = q
__global__ void att_kernel(const float* __restrict__ conp, const float* __restrict__ conh,
                           const float* __restrict__ n2arr,
                           float* __restrict__ att, float* __restrict__ rowsum) {
    int blk = blockIdx.x;
    int p = blk & 63, b = (blk >> 6) & 31, dir = blk >> 11;
    int q = threadIdx.x;
    __shared__ float4 pvL[50];
    const float* pv = conp + (b * SS + p) * (2 * HH) + dir * HH;
    if (q < 50) pvL[q] = ((const float4*)pv)[q];
    __syncthreads();
    const float4* hv = (const float4*)(conh + (b * SS + q) * (2 * HH) + dir * HH);
    float dot = 0.f;
    for (int j = 0; j < 50; ++j) {
        float4 a = pvL[j]; float4 c = hv[j];
        dot = fmaf(a.x, c.x, dot); dot = fmaf(a.y, c.y, dot);
        dot = fmaf(a.z, c.z, dot); dot = fmaf(a.w, c.w, dot);
    }
    float n1 = n2arr[((0 * 2 + dir) * BB + b) * SS + p];
    float n2 = n2arr[((1 * 2 + dir) * BB + b) * SS + q];
    float a = dot / fmaxf(n1 * n2, EPS);
    att[blk * SS + q] = a;
    float rs = a;
#pragma unroll
    for (int off = 32; off >= 1; off >>= 1) rs += __shfl_xor(rs, off, 64);
    if (q == 0) rowsum[blk] = rs;
}

// ---------------------------------------------------------------- column sums of att
__global__ void colsum_kernel(const float* __restrict__ att, float* __restrict__ attcol) {
    int blk = blockIdx.x;  // dir*BB + b
    int q = threadIdx.x;
    const float* base = att + blk * SS * SS;
    float acc = 0.f;
    for (int p = 0; p < SS; ++p) acc += base[p * SS + q];
    attcol[blk * SS + q] = acc;
}

// ---------------------------------------------------------------- att-mean & att-max vectors
// blk = ((side*2+dir)*BB + b)*8 + ht ; 256 threads: s = t>>2, c3 = t&3
__global__ void attvec_kernel(const float* __restrict__ conp, const float* __restrict__ conh,
                              const float* __restrict__ att,
                              const float* __restrict__ rowsum, const float* __restrict__ attcol,
                              float* __restrict__ meanv, float* __restrict__ maxv) {
    int blk = blockIdx.x;
    int ht = blk & 7, b = (blk >> 3) & 31, sd = blk >> 8;
    int dir = sd & 1, side = sd >> 1;
    int t = threadIdx.x;
    __shared__ float attL[SS * 65];
    __shared__ float oppL[SS * 26];
    const float* abase = att + (dir * BB + b) * SS * SS;
    for (int e = t; e < SS * SS; e += 256) {
        int r = e >> 6, c = e & 63;
        float v = abase[e];
        if (side == 0) attL[r * 65 + c] = v;
        else           attL[c * 65 + r] = v;
    }
    const float* opp = (side == 0 ? conh : conp);
    for (int e = t; e < SS * 25; e += 256) {
        int k = e / 25, j = e - k * 25;
        oppL[k * 26 + j] = opp[(b * SS + k) * (2 * HH) + dir * HH + ht * 25 + j];
    }
    __syncthreads();
    int s = t >> 2, c3 = t & 3;
    int j0 = c3 * 7;
    float ms[7], mx[7];
#pragma unroll
    for (int i = 0; i < 7; ++i) { ms[i] = 0.f; mx[i] = -INFINITY; }
    for (int k = 0; k < SS; ++k) {
        float a = attL[s * 65 + k];
        int base = k * 26 + j0;
#pragma unroll
        for (int i = 0; i < 7; ++i) {
            if (j0 + i < 25) {
                float tt = a * oppL[base + i];
                ms[i] += tt;
                mx[i] = fmaxf(mx[i], tt);
            }
        }
    }
    float dn = (side == 0) ? rowsum[(dir * BB + b) * SS + s] : attcol[(dir * BB + b) * SS + s];
    float dd = fmaxf(dn, EPS);
    int obase = (((side * 2 + dir) * BB + b) * SS + s) * HH + ht * 25 + j0;
#pragma unroll
    for (int i = 0; i < 7; ++i) {
        if (j0 + i < 25) {
            meanv[obase + i] = ms[i] / dd;
            maxv[obase + i]  = mx[i];
        }
    }
}

// ---------------------------------------------------------------- mp_match (full/mean/max) + wn
// blk = ((side*2+dir)*BB + b)*SS + s ; 64 threads, lane = (m,l)
__global__ void match_kernel(const float* __restrict__ conp, const float* __restrict__ conh,
                             const float* __restrict__ meanv, const float* __restrict__ maxv,
                             const float* __restrict__ w2t, const float* __restrict__ w2pt,
                             float* __restrict__ out, float* __restrict__ wn) {
    int blk = blockIdx.x;
    int s = blk & 63, b = (blk >> 6) & 31, sd = blk >> 11;
    int dir = sd & 1, side = sd >> 1;
    int t = threadIdx.x;
    __shared__ __align__(16) float x2L[HH];
    __shared__ __align__(16) float xyL[3][HH];
    __shared__ __align__(16) float y2L[3][HH];
    const float* v1 = (side == 0 ? conp : conh) + (b * SS + s) * (2 * HH) + dir * HH;
    const float* opp = (side == 0 ? conh : conp);
    int fidx = (dir == 0) ? (SS - 1) : 0;
    const float* fv = opp + (b * SS + fidx) * (2 * HH) + dir * HH;
    const float* mv = meanv + (((side * 2 + dir) * BB + b) * SS + s) * HH;
    const float* xv = maxv  + (((side * 2 + dir) * BB + b) * SS + s) * HH;
    for (int h = t; h < HH; h += 64) {
        float x = v1[h];
        x2L[h] = x * x;
        float y0 = fv[h], y1 = mv[h], y2v = xv[h];
        xyL[0][h] = x * y0;  y2L[0][h] = y0 * y0;
        xyL[1][h] = x * y1;  y2L[1][h] = y1 * y1;
        xyL[2][h] = x * y2v; y2L[2][h] = y2v * y2v;
    }
    __syncthreads();
    if (t < 60) {
        int m = t / 20, l = t - m * 20;
        const float* wt = w2t + (dir * 3 + m) * 4000 + l * 2;
        float d0 = 0, d1 = 0, a0 = 0, a1 = 0, b0 = 0, b1 = 0;
        for (int h2 = 0; h2 < 100; ++h2) {
            float2 w  = *(const float2*)(wt + h2 * 40);
            float2 xy = *(const float2*)&xyL[m][h2 * 2];
            float2 x2 = *(const float2*)&x2L[h2 * 2];
            float2 yy = *(const float2*)&y2L[m][h2 * 2];
            d0 = fmaf(xy.x, w.x, d0); d1 = fmaf(xy.y, w.y, d1);
            a0 = fmaf(x2.x, w.x, a0); a1 = fmaf(x2.y, w.y, a1);
            b0 = fmaf(yy.x, w.x, b0); b1 = fmaf(yy.y, w.y, b1);
        }
        float d = d0 + d1, a = a0 + a1, bb2 = b0 + b1;
        float cosv = d / fmaxf(sqrtf(a * bb2), EPS);
        int chunk = (m == 0) ? 0 : (m == 1) ? 40 : 60;
        out[side * (BB * SS * 160) + (b * SS + s) * 160 + dir * 80 + chunk + l] = cosv;
    }
    if (t < 20) {
        const float* pw = w2pt + dir * 4000 + t * 2;
        float n0 = 0, n1v = 0;
        for (int h2 = 0; h2 < 100; ++h2) {
            float2 w  = *(const float2*)(pw + h2 * 40);
            float2 x2 = *(const float2*)&x2L[h2 * 2];
            n0  = fmaf(x2.x, w.x, n0);
            n1v = fmaf(x2.y, w.y, n1v);
        }
        wn[blk * LL + t] = sqrtf(n0 + n1v);
    }
}

// ---------------------------------------------------------------- fused pairwise (both sides)
// blk = (dir*BB + b)*8 + itile ; 256 threads = 4 waves; wave handles i = itile*8 + 2w, +1
// lane j = opposite index. Row max (over j) -> mv_p via shuffle; col partial max (over 8 i)
// -> pcm[itile][dirb][j][l].
__global__ __launch_bounds__(256) void pairfused_kernel(
        const float* __restrict__ conp, const float* __restrict__ conh,
        const float* __restrict__ w2c, const float* __restrict__ wn,
        float* __restrict__ out, float* __restrict__ pcm) {
    int blk = blockIdx.x;
    int itile = blk & 7, b = (blk >> 3) & 31, dir = blk >> 8;
    int t = threadIdx.x;
    int j = t & 63;
    __shared__ float B_L[64 * 200];  // 51.2 KB, reused as cmL[4][64][20] after barrier

    // stage B (= conh rows for this dir,b) coalesced
    for (int e = t; e < 64 * 50; e += 256) {
        int row = e / 50, c = e - row * 50;
        float4 v = *(const float4*)(conh + (b * SS + row) * (2 * HH) + dir * HH + c * 4);
        *(float4*)&B_L[row * HH + c * 4] = v;
    }
    __syncthreads();

    int w_ = __builtin_amdgcn_readfirstlane(t >> 6);
    int ia = itile * 8 + w_ * 2, ib = ia + 1;
    const float4* A0 = (const float4*)(conp + (b * SS + ia) * (2 * HH) + dir * HH);
    const float4* A1 = (const float4*)(conp + (b * SS + ib) * (2 * HH) + dir * HH);
    const float4* Wq = (const float4*)(w2c + dir * 4000);
    const float4* Bq = (const float4*)&B_L[j * HH];

    float acc0[LL], acc1[LL];
#pragma unroll
    for (int l = 0; l < LL; ++l) { acc0[l] = 0.f; acc1[l] = 0.f; }

    for (int h4 = 0; h4 < 50; ++h4) {
        float4 bq = Bq[h4];
        float4 a0 = A0[h4];
        float4 a1 = A1[h4];
        float e00 = a0.x * bq.x, e01 = a0.y * bq.y, e02 = a0.z * bq.z, e03 = a0.w * bq.w;
        float e10 = a1.x * bq.x, e11 = a1.y * bq.y, e12 = a1.z * bq.z, e13 = a1.w * bq.w;
        const float4* wr = Wq + h4 * 20;
#pragma unroll
        for (int l = 0; l < LL; ++l) {
            float4 w = wr[l];
            acc0[l] = fmaf(e00, w.x, acc0[l]); acc0[l] = fmaf(e01, w.y, acc0[l]);
            acc0[l] = fmaf(e02, w.z, acc0[l]); acc0[l] = fmaf(e03, w.w, acc0[l]);
            acc1[l] = fmaf(e10, w.x, acc1[l]); acc1[l] = fmaf(e11, w.y, acc1[l]);
            acc1[l] = fmaf(e12, w.z, acc1[l]); acc1[l] = fmaf(e13, w.w, acc1[l]);
        }
    }

    // norms: na (rows, uniform per wave), nb (per lane)
    const float* na0 = wn + (((0 * 2 + dir) * BB + b) * SS + ia) * LL;
    const float* na1 = wn + (((0 * 2 + dir) * BB + b) * SS + ib) * LL;
    const float* nbv = wn + (((1 * 2 + dir) * BB + b) * SS + j) * LL;

    float cm[LL];
    float* outp = out + (b * SS) * 160 + dir * 80 + 20;
#pragma unroll
    for (int l = 0; l < LL; ++l) {
        float nb_ = nbv[l];
        float c0 = acc0[l] / fmaxf(na0[l] * nb_, EPS);
        float c1 = acc1[l] / fmaxf(na1[l] * nb_, EPS);
        cm[l] = fmaxf(c0, c1);
        float r0 = c0, r1 = c1;
#pragma unroll
        for (int off = 32; off >= 1; off >>= 1) {
            r0 = fmaxf(r0, __shfl_xor(r0, off, 64));
            r1 = fmaxf(r1, __shfl_xor(r1, off, 64));
        }
        if (j == 0) {
            outp[ia * 160 + l] = r0;   // mv_p pairwise-max chunk
            outp[ib * 160 + l] = r1;
        }
    }

    // column-partial max over this block's 8 i values
    __syncthreads();                   // everyone done reading B_L
    float* cmL = B_L;                  // [4][64][20]
#pragma unroll
    for (int l = 0; l < LL; ++l) cmL[(w_ * 64 + j) * LL + l] = cm[l];
    __syncthreads();
    int lg = t >> 6;
#pragma unroll
    for (int li = 0; li < 5; ++li) {
        int l = lg * 5 + li;
        float m = cmL[(0 * 64 + j) * LL + l];
        m = fmaxf(m, cmL[(1 * 64 + j) * LL + l]);
        m = fmaxf(m, cmL[(2 * 64 + j) * LL + l]);
        m = fmaxf(m, cmL[(3 * 64 + j) * LL + l]);
        pcm[((itile * 64 + (dir * BB + b)) * 64 + j) * LL + l] = m;
    }
}

// ---------------------------------------------------------------- combine col-max partials -> mv_h
// grid: dir*BB + b ; 256 threads: j = t&63, 5 l's per thread
__global__ void colmax_kernel(const float* __restrict__ pcm, float* __restrict__ out) {
    int dirb = blockIdx.x;
    int b = dirb & 31, dir = dirb >> 5;
    int t = threadIdx.x;
    int j = t & 63, lg = t >> 6;
#pragma unroll
    for (int li = 0; li < 5; ++li) {
        int l = lg * 5 + li;
        float m = -INFINITY;
#pragma unroll
        for (int it = 0; it < 8; ++it)
            m = fmaxf(m, pcm[((it * 64 + dirb) * 64 + j) * LL + l]);
        out[BB * SS * 160 + (b * SS + j) * 160 + dir * 80 + 20 + l] = m;
    }
}

extern "C" void kernel_launch(void* const* d_in, const int* in_sizes, int n_in,
                              void* d_out, int out_size, void* d_ws, size_t ws_size,
                              hipStream_t stream) {
    const float* conp = (const float*)d_in[0];
    const float* conh = (const float*)d_in[1];
    const float* w1 = (const float*)d_in[2];
    const float* w2 = (const float*)d_in[3];
    const float* w3 = (const float*)d_in[4];
    const float* w4 = (const float*)d_in[5];
    const float* w5 = (const float*)d_in[6];
    const float* w6 = (const float*)d_in[7];
    const float* w7 = (const float*)d_in[8];
    const float* w8 = (const float*)d_in[9];
    float* out = (float*)d_out;
    float* ws  = (float*)d_ws;

    float* att    = ws;                        // 262144
    float* rowsum = att + 2 * BB * SS * SS;    // 4096
    float* attcol = rowsum + 2 * BB * SS;      // 4096
    float* n2arr  = attcol + 2 * BB * SS;      // 8192
    float* wn     = n2arr + 4 * BB * SS;       // 163840
    float* w2c    = wn + 4 * BB * SS * LL;     // 8000
    float* w2pt   = w2c + 2 * LL * HH;         // 8000
    float* w2t    = w2pt + 2 * LL * HH;        // 24000
    float* meanv  = w2t + 6 * LL * HH;         // 1638400
    float* maxv   = meanv + 4 * BB * SS * HH;  // 1638400
    float* pcm    = maxv + 4 * BB * SS * HH;   // 655360

    sq_kernel<<<(2 * LL * HH + 255) / 256, 256, 0, stream>>>(w1, w2, w3, w4, w5, w6, w7, w8,
                                                             w2c, w2pt, w2t);
    pnorm_kernel<<<4 * BB * SS / 4, 256, 0, stream>>>(conp, conh, n2arr);
    att_kernel<<<2 * BB * SS, 64, 0, stream>>>(conp, conh, n2arr, att, rowsum);
    colsum_kernel<<<2 * BB, 64, 0, stream>>>(att, attcol);
    attvec_kernel<<<4 * BB * 8, 256, 0, stream>>>(conp, conh, att, rowsum, attcol, meanv, maxv);
    match_kernel<<<4 * BB * SS, 64, 0, stream>>>(conp, conh, meanv, maxv, w2t, w2pt, out, wn);
    pairfused_kernel<<<2 * BB * 8, 256, 0, stream>>>(conp, conh, w2c, wn, out, pcm);
    colmax_kernel<<<2 * BB, 256, 0, stream>>>(pcm, out);
}

// Round 5
// 240.882 us; speedup vs baseline: 1.4437x; 1.0178x over previous
//
#include <hip/hip_runtime.h>
#include <math.h>

#define EPS 1e-8f
#define BB 32
#define SS 64
#define HH 200
#define LL 20
#define BST 204   // padded B_L row stride (204 mod 32 = 12 -> all-32-bank coverage per 8 lanes)

// ws layout (floats):
// att 262144 | n2arr 8192 | wn 163840
// w2c 8000 [dir][h4][l][4] | w2pt 8000 [dir][h2][l][2] | w2t 24000 [dir*3+m][h2][l][2]
// meanv 1638400 | maxv 1638400 | pcm 655360 [itile][dirb][j][l]

// ---------------------------------------------------------------- prep: squared weights + plain norms
// blocks [0,32): weight squaring (3 layouts); blocks [32, 32+2048): plain norms
__global__ void prep_kernel(const float* __restrict__ conp, const float* __restrict__ conh,
                            const float* __restrict__ w1, const float* __restrict__ w2,
                            const float* __restrict__ w3, const float* __restrict__ w4,
                            const float* __restrict__ w5, const float* __restrict__ w6,
                            const float* __restrict__ w7, const float* __restrict__ w8,
                            float* __restrict__ w2c, float* __restrict__ w2pt,
                            float* __restrict__ w2t, float* __restrict__ n2arr) {
    if (blockIdx.x < 32) {
        int idx = blockIdx.x * 256 + threadIdx.x;
        if (idx >= 2 * LL * HH) return;
        int dir = idx / (LL * HH);
        int r = idx % (LL * HH);
        int l = r / HH, h = r % HH;
        int h2 = h >> 1, comp = h & 1;
        float v = (dir == 0 ? w3 : w4)[l * HH + h];
        float sqv = v * v;
        w2c[dir * 4000 + (h >> 2) * 80 + l * 4 + (h & 3)] = sqv;  // [dir][h4][l][4]
        w2pt[(dir * 100 + h2) * 40 + l * 2 + comp] = sqv;          // [dir][h2][l][2]
        const float* wa = dir ? w2 : w1;
        const float* wb = dir ? w6 : w5;
        const float* wc = dir ? w8 : w7;
        float ua = wa[l * HH + h], ub = wb[l * HH + h], uc = wc[l * HH + h];
        w2t[((dir * 3 + 0) * 100 + h2) * 40 + l * 2 + comp] = ua * ua;
        w2t[((dir * 3 + 1) * 100 + h2) * 40 + l * 2 + comp] = ub * ub;
        w2t[((dir * 3 + 2) * 100 + h2) * 40 + l * 2 + comp] = uc * uc;
    } else {
        int t = threadIdx.x;
        int wave = t >> 6, lane = t & 63;
        int e = (blockIdx.x - 32) * 4 + wave;
        int s = e & 63, b = (e >> 6) & 31, sd = e >> 11;
        int dir = sd & 1, side = sd >> 1;
        const float* v = (side ? conh : conp) + (b * SS + s) * (2 * HH) + dir * HH;
        float val = 0.f;
        if (lane < 50) {
            float4 f = ((const float4*)v)[lane];
            val = f.x * f.x + f.y * f.y + f.z * f.z + f.w * f.w;
        }
#pragma unroll
        for (int off = 32; off >= 1; off >>= 1) val += __shfl_xor(val, off, 64);
        if (lane == 0) n2arr[e] = sqrtf(val);
    }
}

// ---------------------------------------------------------------- attention matrix
// blk = (dir*BB+b)*SS + p ; lanes = q
__global__ void att_kernel(const float* __restrict__ conp, const float* __restrict__ conh,
                           const float* __restrict__ n2arr, float* __restrict__ att) {
    int blk = blockIdx.x;
    int p = blk & 63, b = (blk >> 6) & 31, dir = blk >> 11;
    int q = threadIdx.x;
    __shared__ float4 pvL[50];
    const float* pv = conp + (b * SS + p) * (2 * HH) + dir * HH;
    if (q < 50) pvL[q] = ((const float4*)pv)[q];
    __syncthreads();
    const float4* hv = (const float4*)(conh + (b * SS + q) * (2 * HH) + dir * HH);
    float dot = 0.f;
    for (int j = 0; j < 50; ++j) {
        float4 a = pvL[j]; float4 c = hv[j];
        dot = fmaf(a.x, c.x, dot); dot = fmaf(a.y, c.y, dot);
        dot = fmaf(a.z, c.z, dot); dot = fmaf(a.w, c.w, dot);
    }
    float n1 = n2arr[((0 * 2 + dir) * BB + b) * SS + p];
    float n2 = n2arr[((1 * 2 + dir) * BB + b) * SS + q];
    att[blk * SS + q] = dot / fmaxf(n1 * n2, EPS);
}

// ---------------------------------------------------------------- att-mean & att-max vectors
// blk = ((side*2+dir)*BB + b)*8 + ht ; 256 threads: s = t>>2, c3 = t&3
// denominator (row/col sum of att) computed from the LDS tile (reduction dim is k either way)
__global__ void attvec_kernel(const float* __restrict__ conp, const float* __restrict__ conh,
                              const float* __restrict__ att,
                              float* __restrict__ meanv, float* __restrict__ maxv) {
    int blk = blockIdx.x;
    int ht = blk & 7, b = (blk >> 3) & 31, sd = blk >> 8;
    int dir = sd & 1, side = sd >> 1;
    int t = threadIdx.x;
    __shared__ float attL[SS * 65];
    __shared__ float oppL[SS * 26];
    const float* abase = att + (dir * BB + b) * SS * SS;
    for (int e = t; e < SS * SS; e += 256) {
        int r = e >> 6, c = e & 63;
        float v = abase[e];
        if (side == 0) attL[r * 65 + c] = v;
        else           attL[c * 65 + r] = v;
    }
    const float* opp = (side == 0 ? conh : conp);
    for (int e = t; e < SS * 25; e += 256) {
        int k = e / 25, j = e - k * 25;
        oppL[k * 26 + j] = opp[(b * SS + k) * (2 * HH) + dir * HH + ht * 25 + j];
    }
    __syncthreads();
    int s = t >> 2, c3 = t & 3;
    int j0 = c3 * 7;
    float ms[7], mx[7];
#pragma unroll
    for (int i = 0; i < 7; ++i) { ms[i] = 0.f; mx[i] = -INFINITY; }
    float dn = 0.f;
    for (int k = 0; k < SS; ++k) {
        float a = attL[s * 65 + k];
        dn += a;
        int base = k * 26 + j0;
#pragma unroll
        for (int i = 0; i < 7; ++i) {
            if (j0 + i < 25) {
                float tt = a * oppL[base + i];
                ms[i] += tt;
                mx[i] = fmaxf(mx[i], tt);
            }
        }
    }
    float dd = fmaxf(dn, EPS);
    int obase = (((side * 2 + dir) * BB + b) * SS + s) * HH + ht * 25 + j0;
#pragma unroll
    for (int i = 0; i < 7; ++i) {
        if (j0 + i < 25) {
            meanv[obase + i] = ms[i] / dd;
            maxv[obase + i]  = mx[i];
        }
    }
}

// ---------------------------------------------------------------- mp_match (full/mean/max) + wn
// blk = ((side*2+dir)*BB + b)*SS + s ; 64 threads, lane = (m,l)
__global__ void match_kernel(const float* __restrict__ conp, const float* __restrict__ conh,
                             const float* __restrict__ meanv, const float* __restrict__ maxv,
                             const float* __restrict__ w2t, const float* __restrict__ w2pt,
                             float* __restrict__ out, float* __restrict__ wn) {
    int blk = blockIdx.x;
    int s = blk & 63, b = (blk >> 6) & 31, sd = blk >> 11;
    int dir = sd & 1, side = sd >> 1;
    int t = threadIdx.x;
    __shared__ __align__(16) float x2L[HH];
    __shared__ __align__(16) float xyL[3][HH];
    __shared__ __align__(16) float y2L[3][HH];
    const float* v1 = (side == 0 ? conp : conh) + (b * SS + s) * (2 * HH) + dir * HH;
    const float* opp = (side == 0 ? conh : conp);
    int fidx = (dir == 0) ? (SS - 1) : 0;
    const float* fv = opp + (b * SS + fidx) * (2 * HH) + dir * HH;
    const float* mv = meanv + (((side * 2 + dir) * BB + b) * SS + s) * HH;
    const float* xv = maxv  + (((side * 2 + dir) * BB + b) * SS + s) * HH;
    for (int h = t; h < HH; h += 64) {
        float x = v1[h];
        x2L[h] = x * x;
        float y0 = fv[h], y1 = mv[h], y2v = xv[h];
        xyL[0][h] = x * y0;  y2L[0][h] = y0 * y0;
        xyL[1][h] = x * y1;  y2L[1][h] = y1 * y1;
        xyL[2][h] = x * y2v; y2L[2][h] = y2v * y2v;
    }
    __syncthreads();
    if (t < 60) {
        int m = t / 20, l = t - m * 20;
        const float* wt = w2t + (dir * 3 + m) * 4000 + l * 2;
        float d0 = 0, d1 = 0, a0 = 0, a1 = 0, b0 = 0, b1 = 0;
        for (int h2 = 0; h2 < 100; ++h2) {
            float2 w  = *(const float2*)(wt + h2 * 40);
            float2 xy = *(const float2*)&xyL[m][h2 * 2];
            float2 x2 = *(const float2*)&x2L[h2 * 2];
            float2 yy = *(const float2*)&y2L[m][h2 * 2];
            d0 = fmaf(xy.x, w.x, d0); d1 = fmaf(xy.y, w.y, d1);
            a0 = fmaf(x2.x, w.x, a0); a1 = fmaf(x2.y, w.y, a1);
            b0 = fmaf(yy.x, w.x, b0); b1 = fmaf(yy.y, w.y, b1);
        }
        float d = d0 + d1, a = a0 + a1, bb2 = b0 + b1;
        float cosv = d / fmaxf(sqrtf(a * bb2), EPS);
        int chunk = (m == 0) ? 0 : (m == 1) ? 40 : 60;
        out[side * (BB * SS * 160) + (b * SS + s) * 160 + dir * 80 + chunk + l] = cosv;
    }
    if (t < 20) {
        const float* pw = w2pt + dir * 4000 + t * 2;
        float n0 = 0, n1v = 0;
        for (int h2 = 0; h2 < 100; ++h2) {
            float2 w  = *(const float2*)(pw + h2 * 40);
            float2 x2 = *(const float2*)&x2L[h2 * 2];
            n0  = fmaf(x2.x, w.x, n0);
            n1v = fmaf(x2.y, w.y, n1v);
        }
        wn[blk * LL + t] = sqrtf(n0 + n1v);
    }
}

// ---------------------------------------------------------------- fused pairwise (both sides)
// blk = (dir*BB + b)*8 + itile ; 4 waves; wave handles i = itile*8 + 2w, +1 ; lane = j
__global__ __launch_bounds__(256) void pairfused_kernel(
        const float* __restrict__ conp, const float* __restrict__ conh,
        const float* __restrict__ w2c, const float* __restrict__ wn,
        float* __restrict__ out, float* __restrict__ pcm) {
    int blk = blockIdx.x;
    int itile = blk & 7, b = (blk >> 3) & 31, dir = blk >> 8;
    int t = threadIdx.x;
    int j = t & 63;
    __shared__ float B_L[64 * BST];  // 52.2 KB, padded rows; reused as cmL after barrier

    // stage B coalesced (float4 chunks; BST = 4*51 keeps 16B alignment)
    for (int e = t; e < 64 * 50; e += 256) {
        int row = e / 50, c = e - row * 50;
        float4 v = *(const float4*)(conh + (b * SS + row) * (2 * HH) + dir * HH + c * 4);
        *(float4*)&B_L[row * BST + c * 4] = v;
    }
    __syncthreads();

    int w_ = __builtin_amdgcn_readfirstlane(t >> 6);
    int ia = itile * 8 + w_ * 2, ib = ia + 1;
    const float4* A0 = (const float4*)(conp + (b * SS + ia) * (2 * HH) + dir * HH);
    const float4* A1 = (const float4*)(conp + (b * SS + ib) * (2 * HH) + dir * HH);
    const float4* Wq = (const float4*)(w2c + dir * 4000);
    const float4* Bq = (const float4*)&B_L[j * BST];

    float acc0[LL], acc1[LL];
#pragma unroll
    for (int l = 0; l < LL; ++l) { acc0[l] = 0.f; acc1[l] = 0.f; }

    for (int h4 = 0; h4 < 50; ++h4) {
        float4 bq = Bq[h4];
        float4 a0 = A0[h4];
        float4 a1 = A1[h4];
        float e00 = a0.x * bq.x, e01 = a0.y * bq.y, e02 = a0.z * bq.z, e03 = a0.w * bq.w;
        float e10 = a1.x * bq.x, e11 = a1.y * bq.y, e12 = a1.z * bq.z, e13 = a1.w * bq.w;
        const float4* wr = Wq + h4 * 20;
#pragma unroll
        for (int l = 0; l < LL; ++l) {
            float4 w = wr[l];
            acc0[l] = fmaf(e00, w.x, acc0[l]); acc0[l] = fmaf(e01, w.y, acc0[l]);
            acc0[l] = fmaf(e02, w.z, acc0[l]); acc0[l] = fmaf(e03, w.w, acc0[l]);
            acc1[l] = fmaf(e10, w.x, acc1[l]); acc1[l] = fmaf(e11, w.y, acc1[l]);
            acc1[l] = fmaf(e12, w.z, acc1[l]); acc1[l] = fmaf(e13, w.w, acc1[l]);
        }
    }

    const float* na0 = wn + (((0 * 2 + dir) * BB + b) * SS + ia) * LL;
    const float* na1 = wn + (((0 * 2 + dir) * BB + b) * SS + ib) * LL;
    const float* nbv = wn + (((1 * 2 + dir) * BB + b) * SS + j) * LL;

    float cm[LL];
    float* outp = out + (b * SS) * 160 + dir * 80 + 20;
#pragma unroll
    for (int l = 0; l < LL; ++l) {
        float nb_ = nbv[l];
        float c0 = acc0[l] / fmaxf(na0[l] * nb_, EPS);
        float c1 = acc1[l] / fmaxf(na1[l] * nb_, EPS);
        cm[l] = fmaxf(c0, c1);
        float r0 = c0, r1 = c1;
#pragma unroll
        for (int off = 32; off >= 1; off >>= 1) {
            r0 = fmaxf(r0, __shfl_xor(r0, off, 64));
            r1 = fmaxf(r1, __shfl_xor(r1, off, 64));
        }
        if (j == 0) {
            outp[ia * 160 + l] = r0;   // mv_p pairwise-max chunk
            outp[ib * 160 + l] = r1;
        }
    }

    // column-partial max over this block's 8 i values
    __syncthreads();
    float* cmL = B_L;                  // [4][64][20]
#pragma unroll
    for (int l = 0; l < LL; ++l) cmL[(w_ * 64 + j) * LL + l] = cm[l];
    __syncthreads();
    int lg = t >> 6;
#pragma unroll
    for (int li = 0; li < 5; ++li) {
        int l = lg * 5 + li;
        float m = cmL[(0 * 64 + j) * LL + l];
        m = fmaxf(m, cmL[(1 * 64 + j) * LL + l]);
        m = fmaxf(m, cmL[(2 * 64 + j) * LL + l]);
        m = fmaxf(m, cmL[(3 * 64 + j) * LL + l]);
        pcm[((itile * 64 + (dir * BB + b)) * 64 + j) * LL + l] = m;
    }
}

// ---------------------------------------------------------------- combine col-max partials -> mv_h
__global__ void colmax_kernel(const float* __restrict__ pcm, float* __restrict__ out) {
    int dirb = blockIdx.x;
    int b = dirb & 31, dir = dirb >> 5;
    int t = threadIdx.x;
    int j = t & 63, lg = t >> 6;
#pragma unroll
    for (int li = 0; li < 5; ++li) {
        int l = lg * 5 + li;
        float m = -INFINITY;
#pragma unroll
        for (int it = 0; it < 8; ++it)
            m = fmaxf(m, pcm[((it * 64 + dirb) * 64 + j) * LL + l]);
        out[BB * SS * 160 + (b * SS + j) * 160 + dir * 80 + 20 + l] = m;
    }
}

extern "C" void kernel_launch(void* const* d_in, const int* in_sizes, int n_in,
                              void* d_out, int out_size, void* d_ws, size_t ws_size,
                              hipStream_t stream) {
    const float* conp = (const float*)d_in[0];
    const float* conh = (const float*)d_in[1];
    const float* w1 = (const float*)d_in[2];
    const float* w2 = (const float*)d_in[3];
    const float* w3 = (const float*)d_in[4];
    const float* w4 = (const float*)d_in[5];
    const float* w5 = (const float*)d_in[6];
    const float* w6 = (const float*)d_in[7];
    const float* w7 = (const float*)d_in[8];
    const float* w8 = (const float*)d_in[9];
    float* out = (float*)d_out;
    float* ws  = (float*)d_ws;

    float* att    = ws;                        // 262144
    float* n2arr  = att + 2 * BB * SS * SS;    // 8192
    float* wn     = n2arr + 4 * BB * SS;       // 163840
    float* w2c    = wn + 4 * BB * SS * LL;     // 8000
    float* w2pt   = w2c + 2 * LL * HH;         // 8000
    float* w2t    = w2pt + 2 * LL * HH;        // 24000
    float* meanv  = w2t + 6 * LL * HH;         // 1638400
    float* maxv   = meanv + 4 * BB * SS * HH;  // 1638400
    float* pcm    = maxv + 4 * BB * SS * HH;   // 655360

    prep_kernel<<<32 + 4 * BB * SS / 4, 256, 0, stream>>>(conp, conh, w1, w2, w3, w4, w5, w6,
                                                          w7, w8, w2c, w2pt, w2t, n2arr);
    att_kernel<<<2 * BB * SS, 64, 0, stream>>>(conp, conh, n2arr, att);
    attvec_kernel<<<4 * BB * 8, 256, 0, stream>>>(conp, conh, att, meanv, maxv);
    match_kernel<<<4 * BB * SS, 64, 0, stream>>>(conp, conh, meanv, maxv, w2t, w2pt, out, wn);
    pairfused_kernel<<<2 * BB * 8, 256, 0, stream>>>(conp, conh, w2c, wn, out, pcm);
    colmax_kernel<<<2 * BB, 256, 0, stream>>>(pcm, out);
}